// Round 9
// baseline (191.418 us; speedup 1.0000x reference)
//
#include <hip/hip_runtime.h>
#include <hip/hip_bf16.h>

#define SDIM 48
#define SP   110592           // 48^3
#define C_IN 16
#define O_OUT 32
#define T27  27
#define OST  96               // offs row stride (channel-last, 81 used, 96 padded)
#define SROW 776              // S row stride (ush): 32 slots x 24 + 8 pad
#define SLOT 24               // ush per tap slot (16 ch + 8 pad)

typedef __attribute__((ext_vector_type(8))) short bf16x8;
typedef __attribute__((ext_vector_type(4))) float f32x4;
typedef __attribute__((ext_vector_type(2))) float f32x2;

__device__ __forceinline__ float bf2f(unsigned short u) {
    unsigned int x = ((unsigned int)u) << 16;
    return __builtin_bit_cast(float, x);
}
__device__ __forceinline__ unsigned short f2bf(float f) {
    unsigned int x = __builtin_bit_cast(unsigned int, f);
    x += 0x7fffu + ((x >> 16) & 1u);     // RNE
    return (unsigned short)(x >> 16);
}

// ---------- Kernel 0a: x [n][c][sp] fp32 -> xT [n][sp][c] bf16 ---------------
__global__ __launch_bounds__(256)
void prep_xT(const float* __restrict__ x, unsigned short* __restrict__ xT) {
    __shared__ float l[256 * 17];
    const int tid = threadIdx.x;
    const int b   = blockIdx.x;          // 0..863
    const int n   = b / 432;
    const int sp0 = (b - n * 432) * 256;
    #pragma unroll
    for (int c = 0; c < 16; ++c)
        l[tid * 17 + c] = x[((size_t)(n * 16 + c)) * SP + sp0 + tid];
    __syncthreads();
    unsigned int u[8];
    #pragma unroll
    for (int q = 0; q < 8; ++q) {
        unsigned short a = f2bf(l[tid * 17 + 2 * q]);
        unsigned short bb = f2bf(l[tid * 17 + 2 * q + 1]);
        u[q] = (unsigned int)a | ((unsigned int)bb << 16);
    }
    uint4* dst = (uint4*)(xT + ((size_t)(n * SP + sp0 + tid)) * 16);
    dst[0] = make_uint4(u[0], u[1], u[2], u[3]);
    dst[1] = make_uint4(u[4], u[5], u[6], u[7]);
}

// ---------- Kernel 0b: pack offset-conv weights into B-fragment layout -------
__global__ __launch_bounds__(256)
void prep_bfrag(const float* __restrict__ ow, unsigned short* __restrict__ Bf) {
    int idx = blockIdx.x * 256 + threadIdx.x;     // 0..43007
    int r    = idx & 7;
    int lane = (idx >> 3) & 63;
    int snt  = idx >> 9;                          // s*6+nt, 0..83
    int s = snt / 6, nt = snt - s * 6;
    int kk  = ((lane >> 4) << 3) + r;
    int g   = nt * 16 + (lane & 15);
    int tap = 2 * s + (kk >> 4);
    int c   = kk & 15;
    float v = 0.f;
    if (tap < 27 && g < 81) v = ow[((size_t)(g * 16 + c)) * 27 + tap];
    Bf[idx] = f2bf(v);
}

// ---------- Kernel 0c: pack einsum weights into B-frag layout (16 k-steps) ---
// Wf[((s*2+nt)*64 + lane)*8 + r]; s in [0,16); taps 28..31 are zero.
__global__ __launch_bounds__(256)
void prep_wfrag(const float* __restrict__ w, unsigned short* __restrict__ Wf) {
    int idx = blockIdx.x * 256 + threadIdx.x;     // 0..16383
    int r    = idx & 7;
    int lane = (idx >> 3) & 63;
    int snt  = idx >> 9;                          // s*2+nt, 0..31
    int s = snt >> 1, nt = snt & 1;
    int kk  = ((lane >> 4) << 3) + r;
    int o   = nt * 16 + (lane & 15);
    int tap = 2 * s + (kk >> 4);
    int c   = kk & 15;
    float v = 0.f;
    if (tap < 27) v = w[((size_t)(o * 16 + c)) * 27 + tap];
    Wf[idx] = f2bf(v);
}

// ---------- Kernel 1: offset conv as implicit-GEMM MFMA ----------------------
// Output: offs[n][sp][96] bf16 channel-last, contiguous 12KB tile store.
__global__ __launch_bounds__(256)
void offs_conv_mfma(const unsigned short* __restrict__ xT,
                    const unsigned short* __restrict__ Bf,
                    const float* __restrict__ ob,
                    unsigned short* __restrict__ offs) {
    __shared__ unsigned short Alds[256 * 8];      // 4KB staging
    __shared__ unsigned short Tl[64 * 104];       // 13KB epilogue transpose
    const int tid  = threadIdx.x;
    const int lane = tid & 63;
    const int wid  = tid >> 6;
    // XCD-aware chunked swizzle: 3456 = 8 x 432
    const int bid  = (blockIdx.x & 7) * 432 + (blockIdx.x >> 3);
    const int m    = tid & 63;
    const int n    = (bid >= 1728) ? 1 : 0;
    const int sp   = bid * 64 + m - n * SP;
    const int z    = sp / 2304;
    const int rem  = sp - z * 2304;
    const int y    = rem / 48;
    const int xx   = rem - y * 48;
    const int tapoff = wid >> 1;
    const int half   = wid & 1;

    auto stage_load = [&](int s) -> uint4 {
        int tap = 2 * s + tapoff;
        int kd = tap / 9;
        int t2 = tap - kd * 9;
        int kh = t2 / 3;
        int kw = t2 - kh * 3;
        int di = z + kd - 1, hi = y + kh - 1, wi = xx + kw - 1;
        bool ok = (tap < 27) && ((unsigned)di < 48u) && ((unsigned)hi < 48u) &&
                  ((unsigned)wi < 48u);
        uint4 v = make_uint4(0u, 0u, 0u, 0u);
        if (ok) {
            size_t off = ((size_t)(n * SP + (di * 2304 + hi * 48 + wi))) * 16 + half * 8;
            v = *(const uint4*)(xT + off);
        }
        return v;
    };

    f32x4 acc[6];
    #pragma unroll
    for (int t = 0; t < 6; ++t) acc[t] = (f32x4){0.f, 0.f, 0.f, 0.f};

    uint4 v = stage_load(0);
    for (int s = 0; s < 14; ++s) {
        __syncthreads();
        *(uint4*)&Alds[tid * 8] = v;
        __syncthreads();
        if (s < 13) v = stage_load(s + 1);        // prefetch overlaps MFMA
        bf16x8 a = *(const bf16x8*)&Alds[(((lane >> 4) * 64) + (wid * 16) + (lane & 15)) * 8];
        const bf16x8* bp = (const bf16x8*)Bf + (size_t)(s * 6) * 64 + lane;
        #pragma unroll
        for (int nt = 0; nt < 6; ++nt) {
            bf16x8 b = bp[nt * 64];
            acc[nt] = __builtin_amdgcn_mfma_f32_16x16x32_bf16(a, b, acc[nt], 0, 0, 0);
        }
    }

    // epilogue: bias + bf16 into LDS [row][g] (stride 104), then contiguous out
    const int mrow = wid * 16 + ((lane >> 4) << 2);
    #pragma unroll
    for (int nt = 0; nt < 6; ++nt) {
        int g = nt * 16 + (lane & 15);
        float bia = (g < 81) ? ob[g] : 0.f;
        #pragma unroll
        for (int r = 0; r < 4; ++r)
            Tl[(mrow + r) * 104 + g] = f2bf(acc[nt][r] + bia);
    }
    __syncthreads();
    unsigned short* dst = offs + (size_t)bid * (64 * OST);
    #pragma unroll
    for (int k = 0; k < 3; ++k) {
        int idx = k * 256 + tid;                  // 0..767 uint4-chunks
        int row = idx / 12;
        int col = (idx - row * 12) * 8;
        uint4 vv = *(const uint4*)&Tl[row * 104 + col];
        *(uint4*)(dst + row * OST + col) = vv;
    }
}

// ---------- Kernel 2: fused sampling + MFMA, 512-thread single-phase ---------
// Block = 512 threads = 16 points (p=tid>>5) x 32 taps (t=tid&31; 27..31 zero).
// Lanes 0-31 share a p-row -> offset reads fully coalesced (fixes R8's
// 16-line/quarter divergence). Virtual K=512: 16 k-steps over 8 waves.
// VGPR cap 64 (512,8) — this sampler body compiled to 60 under cap 64 (R6);
// if FETCH_SIZE explodes vs ~25MB it spilled — revert cap.
__global__ __launch_bounds__(512, 8)
void deform_fused(const unsigned short* __restrict__ xT,
                  const unsigned short* __restrict__ Wf,
                  const unsigned short* __restrict__ offs,
                  float* __restrict__ out) {
    // S: [16 p][776 ush] = 24832B;  alias Cp: [8 wv][32 o][20 f] = 20480B
    __shared__ __align__(16) unsigned char smem[24832];
    unsigned short* S  = (unsigned short*)smem;
    float*          Cp = (float*)smem;

    const int tid  = threadIdx.x;
    const int lane = tid & 63;
    const int wv   = tid >> 6;                    // wave 0..7
    const int p    = tid >> 5;                    // point 0..15
    const int t    = tid & 31;                    // tap 0..31 (27+ idle)
    // XCD-aware chunked swizzle: 13824 = 8 x 1728
    const int bid  = (blockIdx.x & 7) * 1728 + (blockIdx.x >> 3);
    const int n    = (bid >= 6912) ? 1 : 0;
    const int sp0  = bid * 16 - n * SP;
    const int sp   = sp0 + p;
    const int z    = sp / 2304;
    const int rm   = sp - z * 2304;
    const int y    = rm / 48;
    const int xx   = rm - y * 48;

    const unsigned short* offr = offs + ((size_t)(n * SP + sp)) * OST;
    const uint4* xq4 = (const uint4*)(xT + (size_t)n * SP * 16);

    // ---- phase 1: sample (p, t) -> 16 bf16 channels ----
    uint4 ra = make_uint4(0u, 0u, 0u, 0u);
    uint4 rb = make_uint4(0u, 0u, 0u, 0u);
    if (t < 27) {
        const int kd = t / 9;
        const int t2 = t - kd * 9;
        const int kh = t2 / 3;
        const int kw = t2 - kh * 3;
        float pd = (float)(z + kd - 1)  + bf2f(offr[t]);
        float ph = (float)(y + kh - 1)  + bf2f(offr[27 + t]);
        float pw = (float)(xx + kw - 1) + bf2f(offr[54 + t]);
        float df = floorf(pd), hf = floorf(ph), wf = floorf(pw);
        float fd = pd - df, fh = ph - hf, fw = pw - wf;
        int d0 = (int)df, h0 = (int)hf, w0 = (int)wf;
        float wd0 = ((unsigned)d0       < 48u) ? (1.f - fd) : 0.f;
        float wd1 = ((unsigned)(d0 + 1) < 48u) ? fd : 0.f;
        float wh0 = ((unsigned)h0       < 48u) ? (1.f - fh) : 0.f;
        float wh1 = ((unsigned)(h0 + 1) < 48u) ? fh : 0.f;
        float ww0 = ((unsigned)w0       < 48u) ? (1.f - fw) : 0.f;
        float ww1 = ((unsigned)(w0 + 1) < 48u) ? fw : 0.f;
        int dc0 = min(max(d0,     0), 47) * 2304;
        int dc1 = min(max(d0 + 1, 0), 47) * 2304;
        int hc0 = min(max(h0,     0), 47) * 48;
        int hc1 = min(max(h0 + 1, 0), 47) * 48;
        int wc0 = min(max(w0,     0), 47);
        int wc1 = min(max(w0 + 1, 0), 47);

        float wdh[4] = {wd0 * wh0, wd0 * wh1, wd1 * wh0, wd1 * wh1};
        int   rdh[4] = {dc0 + hc0, dc0 + hc1, dc1 + hc0, dc1 + hc1};

        f32x2 s2v[8];
        #pragma unroll
        for (int q = 0; q < 8; ++q) s2v[q] = (f32x2){0.f, 0.f};

        #pragma unroll
        for (int g2 = 0; g2 < 2; ++g2) {          // 4 corners per batch
            uint4 cv[8];
            float cwt[4];
            #pragma unroll
            for (int pidx = 0; pidx < 2; ++pidx) {
                int jj = g2 * 2 + pidx;           // dh combo
                int i0 = rdh[jj] + wc0;
                int i1 = rdh[jj] + wc1;
                cv[pidx * 4 + 0] = xq4[(size_t)i0 * 2];
                cv[pidx * 4 + 1] = xq4[(size_t)i0 * 2 + 1];
                cv[pidx * 4 + 2] = xq4[(size_t)i1 * 2];
                cv[pidx * 4 + 3] = xq4[(size_t)i1 * 2 + 1];
                cwt[pidx * 2 + 0] = wdh[jj] * ww0;
                cwt[pidx * 2 + 1] = wdh[jj] * ww1;
            }
            #pragma unroll
            for (int pidx = 0; pidx < 2; ++pidx) {
                #pragma unroll
                for (int wsel = 0; wsel < 2; ++wsel) {
                    f32x2 w2;
                    w2.x = cwt[pidx * 2 + wsel];
                    w2.y = w2.x;
                    const uint4& lo4 = cv[pidx * 4 + wsel * 2];
                    const uint4& hi4 = cv[pidx * 4 + wsel * 2 + 1];
                    unsigned int wd_[8] = {lo4.x, lo4.y, lo4.z, lo4.w,
                                           hi4.x, hi4.y, hi4.z, hi4.w};
                    #pragma unroll
                    for (int q = 0; q < 8; ++q) {
                        f32x2 xv;
                        xv.x = __builtin_bit_cast(float, wd_[q] << 16);
                        xv.y = __builtin_bit_cast(float, wd_[q] & 0xffff0000u);
                        s2v[q] = __builtin_elementwise_fma(xv, w2, s2v[q]);
                    }
                }
            }
        }
        unsigned int o_[8];
        #pragma unroll
        for (int q = 0; q < 8; ++q) {
            unsigned int r_;
            asm("v_cvt_pk_bf16_f32 %0, %1, %2" : "=v"(r_) : "v"(s2v[q].x), "v"(s2v[q].y));
            o_[q] = r_;
        }
        ra = make_uint4(o_[0], o_[1], o_[2], o_[3]);
        rb = make_uint4(o_[4], o_[5], o_[6], o_[7]);
    }
    {
        unsigned short* wp_ = S + p * SROW + t * SLOT;
        *(uint4*)wp_       = ra;
        *(uint4*)(wp_ + 8) = rb;
    }
    __syncthreads();

    // ---- phase 2: GEMM M=16,N=32,virtual K=512; wave wv: k-steps 2wv,2wv+1 --
    f32x4 acc0 = (f32x4){0.f, 0.f, 0.f, 0.f};
    f32x4 acc1 = (f32x4){0.f, 0.f, 0.f, 0.f};
    {
        const int pr  = lane & 15;
        const int tl  = lane >> 5;                // tap-local in k-step
        const int chh = (lane >> 4) & 1;          // channel half
        const int kv0 = 2 * wv;
        bf16x8 a0 = *(const bf16x8*)(S + pr * SROW + (2 * kv0 + tl) * SLOT + chh * 8);
        bf16x8 a1 = *(const bf16x8*)(S + pr * SROW + (2 * kv0 + 2 + tl) * SLOT + chh * 8);
        const bf16x8* bp0 = (const bf16x8*)Wf + (size_t)((kv0 + 0) * 2) * 64 + lane;
        const bf16x8* bp1 = (const bf16x8*)Wf + (size_t)((kv0 + 1) * 2) * 64 + lane;
        acc0 = __builtin_amdgcn_mfma_f32_16x16x32_bf16(a0, bp0[0],  acc0, 0, 0, 0);
        acc1 = __builtin_amdgcn_mfma_f32_16x16x32_bf16(a0, bp0[64], acc1, 0, 0, 0);
        acc0 = __builtin_amdgcn_mfma_f32_16x16x32_bf16(a1, bp1[0],  acc0, 0, 0, 0);
        acc1 = __builtin_amdgcn_mfma_f32_16x16x32_bf16(a1, bp1[64], acc1, 0, 0, 0);
    }
    __syncthreads();   // staging reads done -> safe to overwrite with Cpart

    // ---- phase 3: partial-C write + fp32 reduce + store ----
    {
        const int o16 = lane & 15;
        const int m0  = (lane >> 4) << 2;
        *(f32x4*)&Cp[(wv * 32 + o16)      * 20 + m0] = acc0;
        *(f32x4*)&Cp[(wv * 32 + 16 + o16) * 20 + m0] = acc1;
    }
    __syncthreads();

    {
        const int o = tid >> 4;                   // 0..31
        const int m = tid & 15;
        float r0 = 0.f;
        #pragma unroll
        for (int w2 = 0; w2 < 8; ++w2)
            r0 += Cp[(w2 * 32 + o) * 20 + m];
        out[((size_t)(n * O_OUT + o)) * SP + sp0 + m] = r0;
    }
}

// -----------------------------------------------------------------------------
extern "C" void kernel_launch(void* const* d_in, const int* in_sizes, int n_in,
                              void* d_out, int out_size, void* d_ws, size_t ws_size,
                              hipStream_t stream) {
    (void)in_sizes; (void)n_in; (void)out_size; (void)ws_size;
    const float* x      = (const float*)d_in[0];
    const float* weight = (const float*)d_in[1];
    const float* ow     = (const float*)d_in[2];
    const float* ob     = (const float*)d_in[3];
    float* out = (float*)d_out;

    unsigned short* offs_b = (unsigned short*)d_ws;            // 2*SP*96 bf16 = 42.5MB
    unsigned short* xT     = offs_b + (size_t)2 * SP * OST;    // 2*SP*16 bf16 = 7.1MB
    unsigned short* Bf     = xT + (size_t)2 * SP * 16;         // 43008 bf16
    unsigned short* Wf     = Bf + 43008;                       // 16384 bf16

    prep_xT<<<864, 256, 0, stream>>>(x, xT);
    prep_bfrag<<<168, 256, 0, stream>>>(ow, Bf);
    prep_wfrag<<<64, 256, 0, stream>>>(weight, Wf);
    offs_conv_mfma<<<3456, 256, 0, stream>>>(xT, Bf, ob, offs_b);
    deform_fused<<<13824, 512, 0, stream>>>(xT, Wf, offs_b, out);
}

// Round 10
// 168.620 us; speedup vs baseline: 1.1352x; 1.1352x over previous
//
#include <hip/hip_runtime.h>
#include <hip/hip_bf16.h>

#define SDIM 48
#define SP   110592           // 48^3
#define C_IN 16
#define O_OUT 32
#define T27  27
#define OST  96               // offs row stride (channel-last, 81 used, 96 padded)
#define SROW 776              // S row stride (ush): 32 slots x 24 + 8 pad
#define SLOT 24               // ush per tap slot (16 ch + 8 pad)

typedef __attribute__((ext_vector_type(8))) short bf16x8;
typedef __attribute__((ext_vector_type(4))) float f32x4;
typedef __attribute__((ext_vector_type(2))) float f32x2;

__device__ __forceinline__ float bf2f(unsigned short u) {
    unsigned int x = ((unsigned int)u) << 16;
    return __builtin_bit_cast(float, x);
}
__device__ __forceinline__ unsigned short f2bf(float f) {
    unsigned int x = __builtin_bit_cast(unsigned int, f);
    x += 0x7fffu + ((x >> 16) & 1u);     // RNE
    return (unsigned short)(x >> 16);
}

// ---------- Kernel 0a: x [n][c][sp] fp32 -> xT [n][sp][c] bf16 ---------------
__global__ __launch_bounds__(256)
void prep_xT(const float* __restrict__ x, unsigned short* __restrict__ xT) {
    __shared__ float l[256 * 17];
    const int tid = threadIdx.x;
    const int b   = blockIdx.x;          // 0..863
    const int n   = b / 432;
    const int sp0 = (b - n * 432) * 256;
    #pragma unroll
    for (int c = 0; c < 16; ++c)
        l[tid * 17 + c] = x[((size_t)(n * 16 + c)) * SP + sp0 + tid];
    __syncthreads();
    unsigned int u[8];
    #pragma unroll
    for (int q = 0; q < 8; ++q) {
        unsigned short a = f2bf(l[tid * 17 + 2 * q]);
        unsigned short bb = f2bf(l[tid * 17 + 2 * q + 1]);
        u[q] = (unsigned int)a | ((unsigned int)bb << 16);
    }
    uint4* dst = (uint4*)(xT + ((size_t)(n * SP + sp0 + tid)) * 16);
    dst[0] = make_uint4(u[0], u[1], u[2], u[3]);
    dst[1] = make_uint4(u[4], u[5], u[6], u[7]);
}

// ---------- Kernel 0b: pack offset-conv weights into B-fragment layout -------
__global__ __launch_bounds__(256)
void prep_bfrag(const float* __restrict__ ow, unsigned short* __restrict__ Bf) {
    int idx = blockIdx.x * 256 + threadIdx.x;     // 0..43007
    int r    = idx & 7;
    int lane = (idx >> 3) & 63;
    int snt  = idx >> 9;                          // s*6+nt, 0..83
    int s = snt / 6, nt = snt - s * 6;
    int kk  = ((lane >> 4) << 3) + r;
    int g   = nt * 16 + (lane & 15);
    int tap = 2 * s + (kk >> 4);
    int c   = kk & 15;
    float v = 0.f;
    if (tap < 27 && g < 81) v = ow[((size_t)(g * 16 + c)) * 27 + tap];
    Bf[idx] = f2bf(v);
}

// ---------- Kernel 0c: pack einsum weights into B-frag layout (16 k-steps) ---
__global__ __launch_bounds__(256)
void prep_wfrag(const float* __restrict__ w, unsigned short* __restrict__ Wf) {
    int idx = blockIdx.x * 256 + threadIdx.x;     // 0..16383
    int r    = idx & 7;
    int lane = (idx >> 3) & 63;
    int snt  = idx >> 9;                          // s*2+nt, 0..31
    int s = snt >> 1, nt = snt & 1;
    int kk  = ((lane >> 4) << 3) + r;
    int o   = nt * 16 + (lane & 15);
    int tap = 2 * s + (kk >> 4);
    int c   = kk & 15;
    float v = 0.f;
    if (tap < 27) v = w[((size_t)(o * 16 + c)) * 27 + tap];
    Wf[idx] = f2bf(v);
}

// ---------- Kernel 1: offset conv as implicit-GEMM MFMA ----------------------
// Output: offs[n][sp][96] bf16 channel-last, contiguous 12KB tile store.
__global__ __launch_bounds__(256)
void offs_conv_mfma(const unsigned short* __restrict__ xT,
                    const unsigned short* __restrict__ Bf,
                    const float* __restrict__ ob,
                    unsigned short* __restrict__ offs) {
    __shared__ unsigned short Alds[256 * 8];      // 4KB staging
    __shared__ unsigned short Tl[64 * 104];       // 13KB epilogue transpose
    const int tid  = threadIdx.x;
    const int lane = tid & 63;
    const int wid  = tid >> 6;
    // XCD-aware chunked swizzle: 3456 = 8 x 432
    const int bid  = (blockIdx.x & 7) * 432 + (blockIdx.x >> 3);
    const int m    = tid & 63;
    const int n    = (bid >= 1728) ? 1 : 0;
    const int sp   = bid * 64 + m - n * SP;
    const int z    = sp / 2304;
    const int rem  = sp - z * 2304;
    const int y    = rem / 48;
    const int xx   = rem - y * 48;
    const int tapoff = wid >> 1;
    const int half   = wid & 1;

    auto stage_load = [&](int s) -> uint4 {
        int tap = 2 * s + tapoff;
        int kd = tap / 9;
        int t2 = tap - kd * 9;
        int kh = t2 / 3;
        int kw = t2 - kh * 3;
        int di = z + kd - 1, hi = y + kh - 1, wi = xx + kw - 1;
        bool ok = (tap < 27) && ((unsigned)di < 48u) && ((unsigned)hi < 48u) &&
                  ((unsigned)wi < 48u);
        uint4 v = make_uint4(0u, 0u, 0u, 0u);
        if (ok) {
            size_t off = ((size_t)(n * SP + (di * 2304 + hi * 48 + wi))) * 16 + half * 8;
            v = *(const uint4*)(xT + off);
        }
        return v;
    };

    f32x4 acc[6];
    #pragma unroll
    for (int t = 0; t < 6; ++t) acc[t] = (f32x4){0.f, 0.f, 0.f, 0.f};

    uint4 v = stage_load(0);
    for (int s = 0; s < 14; ++s) {
        __syncthreads();
        *(uint4*)&Alds[tid * 8] = v;
        __syncthreads();
        if (s < 13) v = stage_load(s + 1);        // prefetch overlaps MFMA
        bf16x8 a = *(const bf16x8*)&Alds[(((lane >> 4) * 64) + (wid * 16) + (lane & 15)) * 8];
        const bf16x8* bp = (const bf16x8*)Bf + (size_t)(s * 6) * 64 + lane;
        #pragma unroll
        for (int nt = 0; nt < 6; ++nt) {
            bf16x8 b = bp[nt * 64];
            acc[nt] = __builtin_amdgcn_mfma_f32_16x16x32_bf16(a, b, acc[nt], 0, 0, 0);
        }
    }

    // epilogue: bias + bf16 into LDS [row][g] (stride 104), then contiguous out
    const int mrow = wid * 16 + ((lane >> 4) << 2);
    #pragma unroll
    for (int nt = 0; nt < 6; ++nt) {
        int g = nt * 16 + (lane & 15);
        float bia = (g < 81) ? ob[g] : 0.f;
        #pragma unroll
        for (int r = 0; r < 4; ++r)
            Tl[(mrow + r) * 104 + g] = f2bf(acc[nt][r] + bia);
    }
    __syncthreads();
    unsigned short* dst = offs + (size_t)bid * (64 * OST);
    #pragma unroll
    for (int k = 0; k < 3; ++k) {
        int idx = k * 256 + tid;                  // 0..767 uint4-chunks
        int row = idx / 12;
        int col = (idx - row * 12) * 8;
        uint4 vv = *(const uint4*)&Tl[row * 104 + col];
        *(uint4*)(dst + row * OST + col) = vv;
    }
}

// ---------- Kernel 2: fused sampling + MFMA, 512-thread single-phase ---------
// Block = 512 threads = 16 points (p=tid>>5) x 32 taps (t=tid&31; 27..31 zero).
// Lanes 0-31 share a p-row -> offset reads fully coalesced. Virtual K=512.
// REGISTER-CAP HISTORY (do not tighten): cap<=64 on this body spills to
// scratch (R5: FETCH x7, R9: WRITE x5). (512,4) -> cap 128; 256-thread
// versions compiled to 56-60 VGPR under this cap with zero spill.
__global__ __launch_bounds__(512, 4)
void deform_fused(const unsigned short* __restrict__ xT,
                  const unsigned short* __restrict__ Wf,
                  const unsigned short* __restrict__ offs,
                  float* __restrict__ out) {
    // S: [16 p][776 ush] = 24832B;  alias Cp: [8 wv][32 o][20 f] = 20480B
    __shared__ __align__(16) unsigned char smem[24832];
    unsigned short* S  = (unsigned short*)smem;
    float*          Cp = (float*)smem;

    const int tid  = threadIdx.x;
    const int lane = tid & 63;
    const int wv   = tid >> 6;                    // wave 0..7
    const int p    = tid >> 5;                    // point 0..15
    const int t    = tid & 31;                    // tap 0..31 (27+ idle)
    // XCD-aware chunked swizzle: 13824 = 8 x 1728
    const int bid  = (blockIdx.x & 7) * 1728 + (blockIdx.x >> 3);
    const int n    = (bid >= 6912) ? 1 : 0;
    const int sp0  = bid * 16 - n * SP;
    const int sp   = sp0 + p;
    const int z    = sp / 2304;
    const int rm   = sp - z * 2304;
    const int y    = rm / 48;
    const int xx   = rm - y * 48;

    const unsigned short* offr = offs + ((size_t)(n * SP + sp)) * OST;
    const uint4* xq4 = (const uint4*)(xT + (size_t)n * SP * 16);

    // ---- phase 1: sample (p, t) -> 16 bf16 channels ----
    uint4 ra = make_uint4(0u, 0u, 0u, 0u);
    uint4 rb = make_uint4(0u, 0u, 0u, 0u);
    if (t < 27) {
        const int kd = t / 9;
        const int t2 = t - kd * 9;
        const int kh = t2 / 3;
        const int kw = t2 - kh * 3;
        float pd = (float)(z + kd - 1)  + bf2f(offr[t]);
        float ph = (float)(y + kh - 1)  + bf2f(offr[27 + t]);
        float pw = (float)(xx + kw - 1) + bf2f(offr[54 + t]);
        float df = floorf(pd), hf = floorf(ph), wf = floorf(pw);
        float fd = pd - df, fh = ph - hf, fw = pw - wf;
        int d0 = (int)df, h0 = (int)hf, w0 = (int)wf;
        float wd0 = ((unsigned)d0       < 48u) ? (1.f - fd) : 0.f;
        float wd1 = ((unsigned)(d0 + 1) < 48u) ? fd : 0.f;
        float wh0 = ((unsigned)h0       < 48u) ? (1.f - fh) : 0.f;
        float wh1 = ((unsigned)(h0 + 1) < 48u) ? fh : 0.f;
        float ww0 = ((unsigned)w0       < 48u) ? (1.f - fw) : 0.f;
        float ww1 = ((unsigned)(w0 + 1) < 48u) ? fw : 0.f;
        int dc0 = min(max(d0,     0), 47) * 2304;
        int dc1 = min(max(d0 + 1, 0), 47) * 2304;
        int hc0 = min(max(h0,     0), 47) * 48;
        int hc1 = min(max(h0 + 1, 0), 47) * 48;
        int wc0 = min(max(w0,     0), 47);
        int wc1 = min(max(w0 + 1, 0), 47);

        float wdh[4] = {wd0 * wh0, wd0 * wh1, wd1 * wh0, wd1 * wh1};
        int   rdh[4] = {dc0 + hc0, dc0 + hc1, dc1 + hc0, dc1 + hc1};

        f32x2 s2v[8];
        #pragma unroll
        for (int q = 0; q < 8; ++q) s2v[q] = (f32x2){0.f, 0.f};

        #pragma unroll
        for (int g2 = 0; g2 < 2; ++g2) {          // 4 corners per batch
            uint4 cv[8];
            float cwt[4];
            #pragma unroll
            for (int pidx = 0; pidx < 2; ++pidx) {
                int jj = g2 * 2 + pidx;           // dh combo
                int i0 = rdh[jj] + wc0;
                int i1 = rdh[jj] + wc1;
                cv[pidx * 4 + 0] = xq4[(size_t)i0 * 2];
                cv[pidx * 4 + 1] = xq4[(size_t)i0 * 2 + 1];
                cv[pidx * 4 + 2] = xq4[(size_t)i1 * 2];
                cv[pidx * 4 + 3] = xq4[(size_t)i1 * 2 + 1];
                cwt[pidx * 2 + 0] = wdh[jj] * ww0;
                cwt[pidx * 2 + 1] = wdh[jj] * ww1;
            }
            #pragma unroll
            for (int pidx = 0; pidx < 2; ++pidx) {
                #pragma unroll
                for (int wsel = 0; wsel < 2; ++wsel) {
                    f32x2 w2;
                    w2.x = cwt[pidx * 2 + wsel];
                    w2.y = w2.x;
                    const uint4& lo4 = cv[pidx * 4 + wsel * 2];
                    const uint4& hi4 = cv[pidx * 4 + wsel * 2 + 1];
                    unsigned int wd_[8] = {lo4.x, lo4.y, lo4.z, lo4.w,
                                           hi4.x, hi4.y, hi4.z, hi4.w};
                    #pragma unroll
                    for (int q = 0; q < 8; ++q) {
                        f32x2 xv;
                        xv.x = __builtin_bit_cast(float, wd_[q] << 16);
                        xv.y = __builtin_bit_cast(float, wd_[q] & 0xffff0000u);
                        s2v[q] = __builtin_elementwise_fma(xv, w2, s2v[q]);
                    }
                }
            }
        }
        unsigned int o_[8];
        #pragma unroll
        for (int q = 0; q < 8; ++q) {
            unsigned int r_;
            asm("v_cvt_pk_bf16_f32 %0, %1, %2" : "=v"(r_) : "v"(s2v[q].x), "v"(s2v[q].y));
            o_[q] = r_;
        }
        ra = make_uint4(o_[0], o_[1], o_[2], o_[3]);
        rb = make_uint4(o_[4], o_[5], o_[6], o_[7]);
    }
    {
        unsigned short* wp_ = S + p * SROW + t * SLOT;
        *(uint4*)wp_       = ra;
        *(uint4*)(wp_ + 8) = rb;
    }
    __syncthreads();

    // ---- phase 2: GEMM M=16,N=32,virtual K=512; wave wv: k-steps 2wv,2wv+1 --
    f32x4 acc0 = (f32x4){0.f, 0.f, 0.f, 0.f};
    f32x4 acc1 = (f32x4){0.f, 0.f, 0.f, 0.f};
    {
        const int pr  = lane & 15;
        const int tl  = lane >> 5;                // tap-local in k-step
        const int chh = (lane >> 4) & 1;          // channel half
        const int kv0 = 2 * wv;
        bf16x8 a0 = *(const bf16x8*)(S + pr * SROW + (2 * kv0 + tl) * SLOT + chh * 8);
        bf16x8 a1 = *(const bf16x8*)(S + pr * SROW + (2 * kv0 + 2 + tl) * SLOT + chh * 8);
        const bf16x8* bp0 = (const bf16x8*)Wf + (size_t)((kv0 + 0) * 2) * 64 + lane;
        const bf16x8* bp1 = (const bf16x8*)Wf + (size_t)((kv0 + 1) * 2) * 64 + lane;
        acc0 = __builtin_amdgcn_mfma_f32_16x16x32_bf16(a0, bp0[0],  acc0, 0, 0, 0);
        acc1 = __builtin_amdgcn_mfma_f32_16x16x32_bf16(a0, bp0[64], acc1, 0, 0, 0);
        acc0 = __builtin_amdgcn_mfma_f32_16x16x32_bf16(a1, bp1[0],  acc0, 0, 0, 0);
        acc1 = __builtin_amdgcn_mfma_f32_16x16x32_bf16(a1, bp1[64], acc1, 0, 0, 0);
    }
    __syncthreads();   // staging reads done -> safe to overwrite with Cpart

    // ---- phase 3: partial-C write + fp32 reduce + store ----
    {
        const int o16 = lane & 15;
        const int m0  = (lane >> 4) << 2;
        *(f32x4*)&Cp[(wv * 32 + o16)      * 20 + m0] = acc0;
        *(f32x4*)&Cp[(wv * 32 + 16 + o16) * 20 + m0] = acc1;
    }
    __syncthreads();

    {
        const int o = tid >> 4;                   // 0..31
        const int m = tid & 15;
        float r0 = 0.f;
        #pragma unroll
        for (int w2 = 0; w2 < 8; ++w2)
            r0 += Cp[(w2 * 32 + o) * 20 + m];
        out[((size_t)(n * O_OUT + o)) * SP + sp0 + m] = r0;
    }
}

// -----------------------------------------------------------------------------
extern "C" void kernel_launch(void* const* d_in, const int* in_sizes, int n_in,
                              void* d_out, int out_size, void* d_ws, size_t ws_size,
                              hipStream_t stream) {
    (void)in_sizes; (void)n_in; (void)out_size; (void)ws_size;
    const float* x      = (const float*)d_in[0];
    const float* weight = (const float*)d_in[1];
    const float* ow     = (const float*)d_in[2];
    const float* ob     = (const float*)d_in[3];
    float* out = (float*)d_out;

    unsigned short* offs_b = (unsigned short*)d_ws;            // 2*SP*96 bf16 = 42.5MB
    unsigned short* xT     = offs_b + (size_t)2 * SP * OST;    // 2*SP*16 bf16 = 7.1MB
    unsigned short* Bf     = xT + (size_t)2 * SP * 16;         // 43008 bf16
    unsigned short* Wf     = Bf + 43008;                       // 16384 bf16

    prep_xT<<<864, 256, 0, stream>>>(x, xT);
    prep_bfrag<<<168, 256, 0, stream>>>(ow, Bf);
    prep_wfrag<<<64, 256, 0, stream>>>(weight, Wf);
    offs_conv_mfma<<<3456, 256, 0, stream>>>(xT, Bf, ob, offs_b);
    deform_fused<<<13824, 512, 0, stream>>>(xT, Wf, offs_b, out);
}

// Round 11
// 158.438 us; speedup vs baseline: 1.2082x; 1.0643x over previous
//
#include <hip/hip_runtime.h>
#include <hip/hip_bf16.h>

#define SDIM 48
#define SP   110592           // 48^3
#define C_IN 16
#define O_OUT 32
#define T27  27
#define OST  96               // offs row stride (channel-last, 81 used, 96 padded)
#define OLROW 100             // offset-LDS row stride (ush) -> conflict-free

typedef __attribute__((ext_vector_type(8))) short bf16x8;
typedef __attribute__((ext_vector_type(4))) float f32x4;
typedef __attribute__((ext_vector_type(2))) float f32x2;

__device__ __forceinline__ float bf2f(unsigned short u) {
    unsigned int x = ((unsigned int)u) << 16;
    return __builtin_bit_cast(float, x);
}
__device__ __forceinline__ unsigned short f2bf(float f) {
    unsigned int x = __builtin_bit_cast(unsigned int, f);
    x += 0x7fffu + ((x >> 16) & 1u);     // RNE
    return (unsigned short)(x >> 16);
}

// ---------- Kernel 0a: x [n][c][sp] fp32 -> xT [n][sp][c] bf16 ---------------
__global__ __launch_bounds__(256)
void prep_xT(const float* __restrict__ x, unsigned short* __restrict__ xT) {
    __shared__ float l[256 * 17];
    const int tid = threadIdx.x;
    const int b   = blockIdx.x;          // 0..863
    const int n   = b / 432;
    const int sp0 = (b - n * 432) * 256;
    #pragma unroll
    for (int c = 0; c < 16; ++c)
        l[tid * 17 + c] = x[((size_t)(n * 16 + c)) * SP + sp0 + tid];
    __syncthreads();
    unsigned int u[8];
    #pragma unroll
    for (int q = 0; q < 8; ++q) {
        unsigned short a = f2bf(l[tid * 17 + 2 * q]);
        unsigned short bb = f2bf(l[tid * 17 + 2 * q + 1]);
        u[q] = (unsigned int)a | ((unsigned int)bb << 16);
    }
    uint4* dst = (uint4*)(xT + ((size_t)(n * SP + sp0 + tid)) * 16);
    dst[0] = make_uint4(u[0], u[1], u[2], u[3]);
    dst[1] = make_uint4(u[4], u[5], u[6], u[7]);
}

// ---------- Kernel 0b: pack offset-conv weights into B-fragment layout -------
__global__ __launch_bounds__(256)
void prep_bfrag(const float* __restrict__ ow, unsigned short* __restrict__ Bf) {
    int idx = blockIdx.x * 256 + threadIdx.x;     // 0..43007
    int r    = idx & 7;
    int lane = (idx >> 3) & 63;
    int snt  = idx >> 9;                          // s*6+nt, 0..83
    int s = snt / 6, nt = snt - s * 6;
    int kk  = ((lane >> 4) << 3) + r;
    int g   = nt * 16 + (lane & 15);
    int tap = 2 * s + (kk >> 4);
    int c   = kk & 15;
    float v = 0.f;
    if (tap < 27 && g < 81) v = ow[((size_t)(g * 16 + c)) * 27 + tap];
    Bf[idx] = f2bf(v);
}

// ---------- Kernel 0c: pack einsum weights into B-frag layout (16 k-steps) ---
__global__ __launch_bounds__(256)
void prep_wfrag(const float* __restrict__ w, unsigned short* __restrict__ Wf) {
    int idx = blockIdx.x * 256 + threadIdx.x;     // 0..16383
    int r    = idx & 7;
    int lane = (idx >> 3) & 63;
    int snt  = idx >> 9;                          // s*2+nt, 0..31
    int s = snt >> 1, nt = snt & 1;
    int kk  = ((lane >> 4) << 3) + r;
    int o   = nt * 16 + (lane & 15);
    int tap = 2 * s + (kk >> 4);
    int c   = kk & 15;
    float v = 0.f;
    if (tap < 27) v = w[((size_t)(o * 16 + c)) * 27 + tap];
    Wf[idx] = f2bf(v);
}

// ---------- Kernel 1: offset conv as implicit-GEMM MFMA ----------------------
// Output: offs[n][sp][96] bf16 channel-last, contiguous 12KB tile store.
__global__ __launch_bounds__(256)
void offs_conv_mfma(const unsigned short* __restrict__ xT,
                    const unsigned short* __restrict__ Bf,
                    const float* __restrict__ ob,
                    unsigned short* __restrict__ offs) {
    __shared__ unsigned short Alds[256 * 8];      // 4KB staging
    __shared__ unsigned short Tl[64 * 104];       // 13KB epilogue transpose
    const int tid  = threadIdx.x;
    const int lane = tid & 63;
    const int wid  = tid >> 6;
    // XCD-aware chunked swizzle: 3456 = 8 x 432
    const int bid  = (blockIdx.x & 7) * 432 + (blockIdx.x >> 3);
    const int m    = tid & 63;
    const int n    = (bid >= 1728) ? 1 : 0;
    const int sp   = bid * 64 + m - n * SP;
    const int z    = sp / 2304;
    const int rem  = sp - z * 2304;
    const int y    = rem / 48;
    const int xx   = rem - y * 48;
    const int tapoff = wid >> 1;
    const int half   = wid & 1;

    auto stage_load = [&](int s) -> uint4 {
        int tap = 2 * s + tapoff;
        int kd = tap / 9;
        int t2 = tap - kd * 9;
        int kh = t2 / 3;
        int kw = t2 - kh * 3;
        int di = z + kd - 1, hi = y + kh - 1, wi = xx + kw - 1;
        bool ok = (tap < 27) && ((unsigned)di < 48u) && ((unsigned)hi < 48u) &&
                  ((unsigned)wi < 48u);
        uint4 v = make_uint4(0u, 0u, 0u, 0u);
        if (ok) {
            size_t off = ((size_t)(n * SP + (di * 2304 + hi * 48 + wi))) * 16 + half * 8;
            v = *(const uint4*)(xT + off);
        }
        return v;
    };

    f32x4 acc[6];
    #pragma unroll
    for (int t = 0; t < 6; ++t) acc[t] = (f32x4){0.f, 0.f, 0.f, 0.f};

    uint4 v = stage_load(0);
    for (int s = 0; s < 14; ++s) {
        __syncthreads();
        *(uint4*)&Alds[tid * 8] = v;
        __syncthreads();
        if (s < 13) v = stage_load(s + 1);        // prefetch overlaps MFMA
        bf16x8 a = *(const bf16x8*)&Alds[(((lane >> 4) * 64) + (wid * 16) + (lane & 15)) * 8];
        const bf16x8* bp = (const bf16x8*)Bf + (size_t)(s * 6) * 64 + lane;
        #pragma unroll
        for (int nt = 0; nt < 6; ++nt) {
            bf16x8 b = bp[nt * 64];
            acc[nt] = __builtin_amdgcn_mfma_f32_16x16x32_bf16(a, b, acc[nt], 0, 0, 0);
        }
    }

    // epilogue: bias + bf16 into LDS [row][g] (stride 104), then contiguous out
    const int mrow = wid * 16 + ((lane >> 4) << 2);
    #pragma unroll
    for (int nt = 0; nt < 6; ++nt) {
        int g = nt * 16 + (lane & 15);
        float bia = (g < 81) ? ob[g] : 0.f;
        #pragma unroll
        for (int r = 0; r < 4; ++r)
            Tl[(mrow + r) * 104 + g] = f2bf(acc[nt][r] + bia);
    }
    __syncthreads();
    unsigned short* dst = offs + (size_t)bid * (64 * OST);
    #pragma unroll
    for (int k = 0; k < 3; ++k) {
        int idx = k * 256 + tid;                  // 0..767 uint4-chunks
        int row = idx / 12;
        int col = (idx - row * 12) * 8;
        uint4 vv = *(const uint4*)&Tl[row * 104 + col];
        *(uint4*)(dst + row * OST + col) = vv;
    }
}

// ---------- Kernel 2: wave-independent fused sampling + register-A MFMA ------
// 448 threads = 7 waves; wave wv owns k-steps {2wv, 2wv+1} (taps 4wv..4wv+3).
// Lane samples EXACTLY its A-fragment: p=lane&15, tap=2s+(lane>>5),
// channels ((lane>>4)&1)*8.. -> 8x16B gathers/sample, no LDS redistribution,
// no mid-kernel barrier. Offsets preloaded to LDS (coalesced, stride 100).
// REGISTER-CAP HISTORY (do not tighten): cap<=64 on this sampler spills
// (R5: FETCH x7, R9: WRITE x5). (448,4) -> cap 128; R8 compiled 40 VGPR clean.
__global__ __launch_bounds__(448, 4)
void deform_fused(const unsigned short* __restrict__ xT,
                  const unsigned short* __restrict__ Wf,
                  const unsigned short* __restrict__ offs,
                  float* __restrict__ out) {
    __shared__ unsigned short OLDS[16 * OLROW];   // 3.2KB offsets
    __shared__ float Cp[7 * 32 * 20];             // 17.9KB partial-C

    const int tid  = threadIdx.x;
    const int lane = tid & 63;
    const int wv   = tid >> 6;                    // wave 0..6
    const int p    = lane & 15;                   // point (A-frag row)
    const int chh  = (lane >> 4) & 1;             // channel half
    const int tl   = lane >> 5;                   // tap-local in k-step
    // XCD-aware chunked swizzle: 13824 = 8 x 1728
    const int bid  = (blockIdx.x & 7) * 1728 + (blockIdx.x >> 3);
    const int n    = (bid >= 6912) ? 1 : 0;
    const int sp0  = bid * 16 - n * SP;
    const int sp   = sp0 + p;
    const int z    = sp / 2304;
    const int rm   = sp - z * 2304;
    const int y    = rm / 48;
    const int xx   = rm - y * 48;

    // ---- phase 0: coalesced offset preload (16 rows x 96 ush) ----
    if (tid < 192) {
        int row = tid / 12;
        int col = (tid - row * 12) * 8;
        uint4 v = *(const uint4*)(offs + ((size_t)(n * SP + sp0 + row)) * OST + col);
        *(uint4*)&OLDS[row * OLROW + col] = v;
    }
    __syncthreads();

    const uint4* xq4 = (const uint4*)(xT + (size_t)n * SP * 16);

    // ---- per-wave: sample 2 k-steps into register A-frags, MFMA each --------
    f32x4 acc0 = (f32x4){0.f, 0.f, 0.f, 0.f};
    f32x4 acc1 = (f32x4){0.f, 0.f, 0.f, 0.f};

    #pragma unroll
    for (int s2 = 0; s2 < 2; ++s2) {
        const int s   = 2 * wv + s2;              // k-step 0..13
        const int tap = 2 * s + tl;               // 0..27 (27 = zero pad)
        uint4 au = make_uint4(0u, 0u, 0u, 0u);
        if (tap < 27) {
            const int kd = tap / 9;
            const int t2 = tap - kd * 9;
            const int kh = t2 / 3;
            const int kw = t2 - kh * 3;
            float pd = (float)(z + kd - 1)  + bf2f(OLDS[p * OLROW + tap]);
            float ph = (float)(y + kh - 1)  + bf2f(OLDS[p * OLROW + 27 + tap]);
            float pw = (float)(xx + kw - 1) + bf2f(OLDS[p * OLROW + 54 + tap]);
            float df = floorf(pd), hf = floorf(ph), wf = floorf(pw);
            float fd = pd - df, fh = ph - hf, fw = pw - wf;
            int d0 = (int)df, h0 = (int)hf, w0 = (int)wf;
            float wd0 = ((unsigned)d0       < 48u) ? (1.f - fd) : 0.f;
            float wd1 = ((unsigned)(d0 + 1) < 48u) ? fd : 0.f;
            float wh0 = ((unsigned)h0       < 48u) ? (1.f - fh) : 0.f;
            float wh1 = ((unsigned)(h0 + 1) < 48u) ? fh : 0.f;
            float ww0 = ((unsigned)w0       < 48u) ? (1.f - fw) : 0.f;
            float ww1 = ((unsigned)(w0 + 1) < 48u) ? fw : 0.f;
            int dc0 = min(max(d0,     0), 47) * 2304;
            int dc1 = min(max(d0 + 1, 0), 47) * 2304;
            int hc0 = min(max(h0,     0), 47) * 48;
            int hc1 = min(max(h0 + 1, 0), 47) * 48;
            int wc0 = min(max(w0,     0), 47);
            int wc1 = min(max(w0 + 1, 0), 47);

            float wdh[4] = {wd0 * wh0, wd0 * wh1, wd1 * wh0, wd1 * wh1};
            int   rdh[4] = {dc0 + hc0, dc0 + hc1, dc1 + hc0, dc1 + hc1};

            // all 8 corners in flight: 8 x 16B (this lane's channel half only)
            uint4 cv[8];
            float cw[8];
            #pragma unroll
            for (int jj = 0; jj < 8; ++jj) {
                int dh = jj >> 1;
                int ws = jj & 1;
                int idx = rdh[dh] + (ws ? wc1 : wc0);
                cv[jj] = xq4[(size_t)idx * 2 + chh];
                cw[jj] = wdh[dh] * (ws ? ww1 : ww0);
            }

            f32x2 s2v[4];
            #pragma unroll
            for (int q = 0; q < 4; ++q) s2v[q] = (f32x2){0.f, 0.f};
            #pragma unroll
            for (int jj = 0; jj < 8; ++jj) {
                f32x2 w2;
                w2.x = cw[jj]; w2.y = cw[jj];
                unsigned int uu[4] = {cv[jj].x, cv[jj].y, cv[jj].z, cv[jj].w};
                #pragma unroll
                for (int q = 0; q < 4; ++q) {
                    f32x2 xv;
                    xv.x = __builtin_bit_cast(float, uu[q] << 16);
                    xv.y = __builtin_bit_cast(float, uu[q] & 0xffff0000u);
                    s2v[q] = __builtin_elementwise_fma(xv, w2, s2v[q]);
                }
            }
            unsigned int o_[4];
            #pragma unroll
            for (int q = 0; q < 4; ++q) {
                unsigned int r_;
                asm("v_cvt_pk_bf16_f32 %0, %1, %2" : "=v"(r_) : "v"(s2v[q].x), "v"(s2v[q].y));
                o_[q] = r_;
            }
            au = make_uint4(o_[0], o_[1], o_[2], o_[3]);
        }
        bf16x8 a = __builtin_bit_cast(bf16x8, au);
        const bf16x8* bp = (const bf16x8*)Wf + (size_t)(s * 2) * 64 + lane;
        acc0 = __builtin_amdgcn_mfma_f32_16x16x32_bf16(a, bp[0],  acc0, 0, 0, 0);
        acc1 = __builtin_amdgcn_mfma_f32_16x16x32_bf16(a, bp[64], acc1, 0, 0, 0);
    }

    // ---- tail: partial-C write + fp32 reduce + store ----
    {
        const int o16 = lane & 15;
        const int m0  = (lane >> 4) << 2;
        *(f32x4*)&Cp[(wv * 32 + o16)      * 20 + m0] = acc0;
        *(f32x4*)&Cp[(wv * 32 + 16 + o16) * 20 + m0] = acc1;
    }
    __syncthreads();

    #pragma unroll
    for (int rep = 0; rep < 2; ++rep) {
        int i = tid + rep * 448;
        if (rep == 0 || tid < 64) {
            int o = i >> 4;                       // 0..31
            int m = i & 15;
            float r0 = 0.f;
            #pragma unroll
            for (int w2 = 0; w2 < 7; ++w2)
                r0 += Cp[(w2 * 32 + o) * 20 + m];
            out[((size_t)(n * O_OUT + o)) * SP + sp0 + m] = r0;
        }
    }
}

// -----------------------------------------------------------------------------
extern "C" void kernel_launch(void* const* d_in, const int* in_sizes, int n_in,
                              void* d_out, int out_size, void* d_ws, size_t ws_size,
                              hipStream_t stream) {
    (void)in_sizes; (void)n_in; (void)out_size; (void)ws_size;
    const float* x      = (const float*)d_in[0];
    const float* weight = (const float*)d_in[1];
    const float* ow     = (const float*)d_in[2];
    const float* ob     = (const float*)d_in[3];
    float* out = (float*)d_out;

    unsigned short* offs_b = (unsigned short*)d_ws;            // 2*SP*96 bf16 = 42.5MB
    unsigned short* xT     = offs_b + (size_t)2 * SP * OST;    // 2*SP*16 bf16 = 7.1MB
    unsigned short* Bf     = xT + (size_t)2 * SP * 16;         // 43008 bf16
    unsigned short* Wf     = Bf + 43008;                       // 16384 bf16

    prep_xT<<<864, 256, 0, stream>>>(x, xT);
    prep_bfrag<<<168, 256, 0, stream>>>(ow, Bf);
    prep_wfrag<<<64, 256, 0, stream>>>(weight, Wf);
    offs_conv_mfma<<<3456, 256, 0, stream>>>(xT, Bf, ob, offs_b);
    deform_fused<<<13824, 448, 0, stream>>>(xT, Wf, offs_b, out);
}